// Round 13
// baseline (520.079 us; speedup 1.0000x reference)
//
#include <hip/hip_runtime.h>
#include <cstdint>

typedef unsigned short u16;
typedef unsigned int u32;
typedef __attribute__((ext_vector_type(8))) short s8v;   // 8 bf16 (4 VGPRs)
typedef __attribute__((ext_vector_type(4))) float f4v;   // MFMA acc

#define FCH 256

__device__ __forceinline__ float bf2f(u16 u){ return __uint_as_float(((u32)u)<<16); }
__device__ __forceinline__ u16 f2bf(float x){
  u32 u = __float_as_uint(x);
  u += 0x7fffu + ((u>>16)&1u);
  return (u16)(u>>16);
}
// Fast reciprocal (v_rcp_f32, ~1e-5 rel err; bf16 outputs tolerate easily).
__device__ __forceinline__ float rcpf(float x){ return __builtin_amdgcn_rcpf(x); }
__device__ __forceinline__ uint4 pack8(float4 a, float4 b){
  uint4 o;
  o.x = (u32)f2bf(a.x) | ((u32)f2bf(a.y)<<16);
  o.y = (u32)f2bf(a.z) | ((u32)f2bf(a.w)<<16);
  o.z = (u32)f2bf(b.x) | ((u32)f2bf(b.y)<<16);
  o.w = (u32)f2bf(b.z) | ((u32)f2bf(b.w)<<16);
  return o;
}
__device__ __forceinline__ float seluf(float x){
  const float sc = 1.0507009873554805f, al = 1.6732632423543772f;
  return x > 0.f ? sc*x : sc*al*(__expf(x)-1.f);
}
// Masked 16B load: AND each dword with m (m=0 zeroes the fragment).
__device__ __forceinline__ s8v ldmask(const u16* p, u32 m){
  uint4 r = *reinterpret_cast<const uint4*>(p);
  r.x &= m; r.y &= m; r.z &= m; r.w &= m;
  s8v v; *reinterpret_cast<uint4*>(&v) = r;
  return v;
}
// XCD-stripe swizzle.
__device__ __forceinline__ int xcd_tile(int bid, int nT8){
  return nT8 ? ((bid & 7) * nT8 + (bid >> 3)) : bid;
}

// ---------------------------------------------------------------------------
// Weight packing (fp32 -> bf16 fragments): lane l slot j of frag (kc,nt) =
// B[kc*32 + (l>>4)*8 + j][nt*16 + (l&15)]  (16B/lane contiguous)
// ---------------------------------------------------------------------------
__global__ __launch_bounds__(256) void pack_kernel(
    const float* __restrict__ Wc, const float* __restrict__ Wf, const float* __restrict__ Wg,
    const float* __restrict__ Wr, const float* __restrict__ Ws,
    const float* __restrict__ Wd1, const float* __restrict__ Wd2,
    u16* __restrict__ Bp1, u16* __restrict__ Bp2, u16* __restrict__ Bp0,
    u16* __restrict__ BpD1, u16* __restrict__ BpD2)
{
  int gid = blockIdx.x*256 + threadIdx.x;
  int frag = gid >> 6;
  int lane = gid & 63;
  int q = lane >> 4, i15 = lane & 15;
  u16 v[8];
  u16* dst;
  if (frag < 4096) {                       // Bp1: [Wf|Wg] K=512 (tap-major)
    int layer = frag >> 9, rem = frag & 511;
    int kc = rem >> 5, nt = rem & 31;
    int n = nt*16 + i15;
    const float* W = (n < 256) ? Wf : Wg;
    int nn = (n < 256) ? n : n - 256;
    #pragma unroll
    for (int j = 0; j < 8; ++j) {
      int k = kc*32 + q*8 + j;
      int tap = k >> 8, cin = k & 255;
      v[j] = f2bf(W[((size_t)((layer*2 + tap)*256 + cin))*256 + nn]);
    }
    dst = Bp1 + (size_t)frag*512 + lane*8;
  } else if (frag < 6144) {                // Bp2: [Wr|Ws] K=256
    int f = frag - 4096;
    int layer = f >> 8, rem = f & 255;
    int kc = rem >> 5, nt = rem & 31;
    int n = nt*16 + i15;
    const float* W = (n < 256) ? Wr : Ws;
    int nn = (n < 256) ? n : n - 256;
    #pragma unroll
    for (int j = 0; j < 8; ++j) {
      int k = kc*32 + q*8 + j;
      v[j] = f2bf(W[((size_t)(layer*256 + k))*256 + nn]);
    }
    dst = Bp2 + (size_t)f*512 + lane*8;
  } else if (frag < 6208) {                // Bp0: Wc K=128
    int f = frag - 6144;
    int kc = f >> 4, nt = f & 15;
    int n = nt*16 + i15;
    #pragma unroll
    for (int j = 0; j < 8; ++j) {
      int k = kc*32 + q*8 + j;
      int tap = k >> 6, cin = k & 63;
      v[j] = f2bf(Wc[(size_t)(tap*64 + cin)*256 + n]);
    }
    dst = Bp0 + (size_t)f*512 + lane*8;
  } else if (frag < 6240) {                // BpD1: Wd1 [256,64]
    int f = frag - 6208;
    int kc = f >> 2, nt = f & 3;
    int n = nt*16 + i15;
    #pragma unroll
    for (int j = 0; j < 8; ++j) {
      int k = kc*32 + q*8 + j;
      v[j] = f2bf(Wd1[(size_t)k*64 + n]);
    }
    dst = BpD1 + (size_t)f*512 + lane*8;
  } else if (frag < 6248) {                // BpD2: Wd2 [64,64]
    int f = frag - 6240;
    int kc = f >> 2, nt = f & 3;
    int n = nt*16 + i15;
    #pragma unroll
    for (int j = 0; j < 8; ++j) {
      int k = kc*32 + q*8 + j;
      v[j] = f2bf(Wd2[(size_t)k*64 + n]);
    }
    dst = BpD2 + (size_t)f*512 + lane*8;
  } else return;
  uint4 o;
  o.x = (u32)v[0] | ((u32)v[1] << 16);
  o.y = (u32)v[2] | ((u32)v[3] << 16);
  o.z = (u32)v[4] | ((u32)v[5] << 16);
  o.w = (u32)v[6] | ((u32)v[7] << 16);
  *reinterpret_cast<uint4*>(dst) = o;
}

// ---------------------------------------------------------------------------
// Initial causal conv (dilation 1, no bias): out0 = [x[t-1]|x[t]] @ cat(Wc)
// ---------------------------------------------------------------------------
__global__ __launch_bounds__(256, 2) void conv0_kernel(
    const float* __restrict__ x, u16* __restrict__ outBf,
    const u16* __restrict__ Bp0, int nT8)
{
  __shared__ __align__(16) u16 ldsA[2][2048];
  const int tid = threadIdx.x;
  const int w = tid >> 6, lane = tid & 63, q = lane >> 4, i15 = lane & 15;
  const int rb = xcd_tile(blockIdx.x, nT8) * 64;
  const int sm = tid >> 2, sg = tid & 3;
  const int grow = rb + sm;
  const int tpos = grow & 4095;
  const int sunit = ((sm >> 4)*64 + sg*16 + ((sm & 15) ^ (sg << 1))) * 8;
  const int runit = (q*16 + (i15 ^ (q << 1))) * 8;

  f4v acc[4][4];
  #pragma unroll
  for (int jj = 0; jj < 4; ++jj)
    #pragma unroll
    for (int mt = 0; mt < 4; ++mt)
      acc[jj][mt] = (f4v){0.f,0.f,0.f,0.f};

  float4 f0 = {0.f,0.f,0.f,0.f}, f1 = {0.f,0.f,0.f,0.f};
  if (tpos >= 1) {
    const float* px = x + (size_t)(grow-1)*64 + sg*8;
    f0 = *reinterpret_cast<const float4*>(px);
    f1 = *reinterpret_cast<const float4*>(px + 4);
  }
  *reinterpret_cast<uint4*>(&ldsA[0][sunit]) = pack8(f0, f1);
  s8v bcur[4], bnxt[4];
  #pragma unroll
  for (int jj = 0; jj < 4; ++jj)
    bcur[jj] = *reinterpret_cast<const s8v*>(Bp0 + ((size_t)(w + 4*jj)*64 + lane)*8);
  __syncthreads();

  for (int kc = 0; kc < 4; ++kc) {
    const int cur = kc & 1;
    uint4 an = {0u,0u,0u,0u};
    if (kc < 3) {
      int kg = (kc+1)*32 + sg*8;
      int tap = kg >> 6, col = kg & 63;
      float4 g0 = {0.f,0.f,0.f,0.f}, g1 = {0.f,0.f,0.f,0.f};
      if (tap) {
        const float* px = x + (size_t)grow*64 + col;
        g0 = *reinterpret_cast<const float4*>(px);
        g1 = *reinterpret_cast<const float4*>(px + 4);
      } else if (tpos >= 1) {
        const float* px = x + (size_t)(grow-1)*64 + col;
        g0 = *reinterpret_cast<const float4*>(px);
        g1 = *reinterpret_cast<const float4*>(px + 4);
      }
      an = pack8(g0, g1);
      #pragma unroll
      for (int jj = 0; jj < 4; ++jj)
        bnxt[jj] = *reinterpret_cast<const s8v*>(Bp0 + (((size_t)(kc+1)*16 + (w + 4*jj))*64 + lane)*8);
    }
    s8v af[4];
    #pragma unroll
    for (int mt = 0; mt < 4; ++mt)
      af[mt] = *reinterpret_cast<const s8v*>(&ldsA[cur][mt*512 + runit]);
    #pragma unroll
    for (int jj = 0; jj < 4; ++jj)
      #pragma unroll
      for (int mt = 0; mt < 4; ++mt)
        acc[jj][mt] = __builtin_amdgcn_mfma_f32_16x16x32_bf16(af[mt], bcur[jj], acc[jj][mt], 0,0,0);
    if (kc < 3) {
      *reinterpret_cast<uint4*>(&ldsA[cur ^ 1][sunit]) = an;
      #pragma unroll
      for (int jj = 0; jj < 4; ++jj) bcur[jj] = bnxt[jj];
    }
    __syncthreads();
  }

  #pragma unroll
  for (int jj = 0; jj < 4; ++jj) {
    const int cc = (w + 4*jj)*16 + i15;
    #pragma unroll
    for (int mt = 0; mt < 4; ++mt)
      #pragma unroll
      for (int r = 0; r < 4; ++r) {
        const int g2 = rb + mt*16 + q*4 + r;
        outBf[(size_t)g2*FCH + cc] = f2bf(acc[jj][mt][r]);
      }
  }
}

// ---------------------------------------------------------------------------
// One WaveNet residual layer (R12 core: M=32, 256 thr, 1024 blocks, A 4-slot
// ring lead-3, B dist-2 half-chunk, one barrier, rcpf, readfirstlane), plus:
//  - skv (old skip) PREFETCHED before stage 2 (HBM/L3-cold; was exposed at
//    epilogue; now hidden under 16 MFMA steps)
//  - last==1: final head FUSED (head is row-local): selu(skip)->ldsZ(reuse)
//    -> @Wd1+bd1,selu -> ldsH2 -> @Wd2+bd2 -> fp32 out. Removes final_kernel
//    launch + L8 skipB/outBf stores + final's skipB HBM re-read.
// ---------------------------------------------------------------------------
__global__ __launch_bounds__(256, 3) void layer_kernel(
    const u16* __restrict__ inBf, u16* __restrict__ outBf,
    u16* __restrict__ skipB,
    const u16* __restrict__ Bp1, const u16* __restrict__ Bp2,
    const float* __restrict__ br, const float* __restrict__ bs,
    const u16* __restrict__ BpD1, const u16* __restrict__ BpD2,
    const float* __restrict__ bd1, const float* __restrict__ bd2,
    float* __restrict__ outp,
    int dil, int first, int last, int nT8)
{
  __shared__ __align__(16) u16 ldsZ[32*264];     // 16.9 KB (reused as H when last)
  __shared__ __align__(16) u16 ldsH2[32*72];     // 4.6 KB (head only)
  const int tid = threadIdx.x;
  const int w = __builtin_amdgcn_readfirstlane(tid >> 6);   // wave-uniform -> SGPR
  const int lane = tid & 63, q = lane >> 4, i15 = lane & 15;
  const int rb = xcd_tile(blockIdx.x, nT8) * 32;

  f4v acc[8][2];   // [jj: nt=w+4*jj][mt]
  #pragma unroll
  for (int jj = 0; jj < 8; ++jj)
    #pragma unroll
    for (int mt = 0; mt < 2; ++mt)
      acc[jj][mt] = (f4v){0.f,0.f,0.f,0.f};

  // ---------------- stage 1: A 4-slot ring (3-chunk lead), B dist-2 ---------
  {
    const u16* a0p[2];   // tap0: row t-dil (safe addr; mask zeroes invalid)
    const u16* a1p[2];   // tap1: row t
    u32 am[2];
    #pragma unroll
    for (int mt = 0; mt < 2; ++mt) {
      const int row = rb + mt*16 + i15;
      const bool v = (row & 4095) >= dil;
      a0p[mt] = inBf + (size_t)(v ? row - dil : row)*FCH + q*8;
      a1p[mt] = inBf + (size_t)row*FCH + q*8;
      am[mt]  = v ? 0xffffffffu : 0u;
    }

    s8v bb[3][4], aa[4][2];
    // prologue B: steps 0,1 (chunk 0 halves); prologue A: chunks 0,1,2
    #pragma unroll
    for (int j2 = 0; j2 < 4; ++j2) {
      bb[0][j2] = *reinterpret_cast<const s8v*>(Bp1 + ((size_t)(w + 4*j2)*64 + lane)*8);
      bb[1][j2] = *reinterpret_cast<const s8v*>(Bp1 + ((size_t)(w + 16 + 4*j2)*64 + lane)*8);
    }
    #pragma unroll
    for (int c = 0; c < 3; ++c)
      #pragma unroll
      for (int mt = 0; mt < 2; ++mt)
        aa[c][mt] = ldmask(a0p[mt] + c*32, am[mt]);

    #pragma unroll
    for (int s = 0; s < 32; ++s) {
      const int kc = s >> 1, h = s & 1;
      if (s + 2 < 32) {                      // B: dist-2 half-chunk prefetch
        const int sp = s + 2, kcp = sp >> 1, hp = sp & 1;
        #pragma unroll
        for (int j2 = 0; j2 < 4; ++j2)
          bb[sp % 3][j2] = *reinterpret_cast<const s8v*>(
              Bp1 + (((size_t)kcp*32 + (w + 16*hp + 4*j2))*64 + lane)*8);
      }
      if (h == 0 && kc + 3 < 16) {           // A: 3-chunk (6-step) lead
        const int ca = kc + 3;               // slot (ca&3)=(kc-1)&3: consumer
        if (ca < 8) {                        // finished at step 2kc-1  -> safe
          #pragma unroll
          for (int mt = 0; mt < 2; ++mt)
            aa[ca & 3][mt] = ldmask(a0p[mt] + ca*32, am[mt]);
        } else {
          #pragma unroll
          for (int mt = 0; mt < 2; ++mt)
            aa[ca & 3][mt] = *reinterpret_cast<const s8v*>(a1p[mt] + (ca - 8)*32);
        }
      }
      __builtin_amdgcn_s_setprio(1);
      #pragma unroll
      for (int j2 = 0; j2 < 4; ++j2)
        #pragma unroll
        for (int mt = 0; mt < 2; ++mt)
          acc[h*4 + j2][mt] = __builtin_amdgcn_mfma_f32_16x16x32_bf16(
              aa[kc & 3][mt], bb[s % 3][j2], acc[h*4 + j2][mt], 0,0,0);
      __builtin_amdgcn_s_setprio(0);
    }
  }

  // -------- issue stage-2 steps 0,1 B loads now (latency hides under exp) ---
  s8v s2b[3][4];
  #pragma unroll
  for (int j2 = 0; j2 < 4; ++j2) {
    s2b[0][j2] = *reinterpret_cast<const s8v*>(Bp2 + ((size_t)(w + 4*j2)*64 + lane)*8);
    s2b[1][j2] = *reinterpret_cast<const s8v*>(Bp2 + ((size_t)(w + 16 + 4*j2)*64 + lane)*8);
  }
  // -------- prefetch old skip NOW (HBM/L3-cold ~500-900cy; hides under
  // stage-2 MFMA). resv (inBf) stays in epilogue: stage-1 just read those
  // rows -> L1-hot.
  u16 skv[4][2][4];
  if (!first) {
    #pragma unroll
    for (int jj = 0; jj < 4; ++jj) {
      const int cc = (w + 4*jj)*16 + i15;
      #pragma unroll
      for (int mt = 0; mt < 2; ++mt)
        #pragma unroll
        for (int r = 0; r < 4; ++r)
          skv[jj][mt][r] = skipB[(size_t)(rb + mt*16 + q*4 + r)*FCH + cc];
    }
  }

  // ---------------- activation: Z -> LDS (C-layout -> row-major) ------------
  #pragma unroll
  for (int jj = 0; jj < 4; ++jj) {
    const int colb = (w + 4*jj)*16 + i15;
    #pragma unroll
    for (int mt = 0; mt < 2; ++mt)
      #pragma unroll
      for (int r = 0; r < 4; ++r) {
        float f = acc[jj][mt][r];
        float g = acc[jj+4][mt][r];
        float z = (1.f - 2.f*rcpf(__expf(2.f*f) + 1.f)) * rcpf(1.f + __expf(-g));
        ldsZ[(mt*16 + q*4 + r)*264 + colb] = f2bf(z);
      }
  }
  // zero acc for stage 2 (residual/skip/bias added in epilogue, f32)
  #pragma unroll
  for (int jj = 0; jj < 8; ++jj)
    #pragma unroll
    for (int mt = 0; mt < 2; ++mt)
      acc[jj][mt] = (f4v){0.f,0.f,0.f,0.f};
  __syncthreads();

  // ---------------- stage 2: half-chunk dist-2 (B global, A LDS) ------------
  {
    s8v zf[2][2];
    #pragma unroll
    for (int mt = 0; mt < 2; ++mt)
      zf[0][mt] = *reinterpret_cast<const s8v*>(&ldsZ[(mt*16 + i15)*264 + q*8]);
    #pragma unroll
    for (int s = 0; s < 16; ++s) {
      const int kc = s >> 1, h = s & 1;
      if (s + 2 < 16) {
        const int sp = s + 2, kcp = sp >> 1, hp = sp & 1;
        #pragma unroll
        for (int j2 = 0; j2 < 4; ++j2)
          s2b[sp % 3][j2] = *reinterpret_cast<const s8v*>(
              Bp2 + (((size_t)kcp*32 + (w + 16*hp + 4*j2))*64 + lane)*8);
        if (hp == 0) {
          #pragma unroll
          for (int mt = 0; mt < 2; ++mt)
            zf[kcp & 1][mt] = *reinterpret_cast<const s8v*>(&ldsZ[(mt*16 + i15)*264 + kcp*32 + q*8]);
        }
      }
      __builtin_amdgcn_s_setprio(1);
      #pragma unroll
      for (int j2 = 0; j2 < 4; ++j2)
        #pragma unroll
        for (int mt = 0; mt < 2; ++mt)
          acc[h*4 + j2][mt] = __builtin_amdgcn_mfma_f32_16x16x32_bf16(
              zf[kc & 1][mt], s2b[s % 3][j2], acc[h*4 + j2][mt], 0,0,0);
      __builtin_amdgcn_s_setprio(0);
    }
  }

  // ---------------- epilogue: residual out (dead when last) -----------------
  if (!last) {
    u16 resv[4][2][4];
    #pragma unroll
    for (int jj = 0; jj < 4; ++jj) {
      const int cc = (w + 4*jj)*16 + i15;
      #pragma unroll
      for (int mt = 0; mt < 2; ++mt)
        #pragma unroll
        for (int r = 0; r < 4; ++r)
          resv[jj][mt][r] = inBf[(size_t)(rb + mt*16 + q*4 + r)*FCH + cc];
    }
    #pragma unroll
    for (int jj = 0; jj < 4; ++jj) {
      const int cc = (w + 4*jj)*16 + i15;
      const float bias = br[cc];
      #pragma unroll
      for (int mt = 0; mt < 2; ++mt)
        #pragma unroll
        for (int r = 0; r < 4; ++r) {
          const int g2 = rb + mt*16 + q*4 + r;
          float vv = acc[jj][mt][r] + bias + bf2f(resv[jj][mt][r]);
          outBf[(size_t)g2*FCH + cc] = f2bf(vv);
        }
    }
    // skip out
    #pragma unroll
    for (int jj = 4; jj < 8; ++jj) {
      const int cc = (jj - 4 + 0)*0 + ((w + 4*jj - 16 - 4*4 + 16))*0; // (unused)
      const int cc2 = ((w + 4*jj) - 16)*16 + i15;
      const float bias = bs[cc2];
      #pragma unroll
      for (int mt = 0; mt < 2; ++mt)
        #pragma unroll
        for (int r = 0; r < 4; ++r) {
          const int g2 = rb + mt*16 + q*4 + r;
          float vv = acc[jj][mt][r] + bias;
          if (!first) vv += bf2f(skv[jj-4][mt][r]);
          skipB[(size_t)g2*FCH + cc2] = f2bf(vv);
        }
    }
    return;
  }

  // ================= last layer: fused final head ===========================
  // all stage-2 ldsZ reads complete before overwrite
  __syncthreads();
  // H = selu(skip_final) -> ldsZ (row-major, stride 264)
  #pragma unroll
  for (int jj = 4; jj < 8; ++jj) {
    const int cc = ((w + 4*jj) - 16)*16 + i15;
    const float bias = bs[cc];
    #pragma unroll
    for (int mt = 0; mt < 2; ++mt)
      #pragma unroll
      for (int r = 0; r < 4; ++r) {
        float vv = acc[jj][mt][r] + bias;
        if (!first) vv += bf2f(skv[jj-4][mt][r]);
        ldsZ[(mt*16 + q*4 + r)*264 + cc] = f2bf(seluf(vv));
      }
  }
  __syncthreads();

  // D1: h[32x256] @ Wd1[256x64] + bd1, selu -> ldsH2 (stride 72)
  f4v a1[2];
  #pragma unroll
  for (int mt = 0; mt < 2; ++mt) a1[mt] = (f4v){0.f,0.f,0.f,0.f};
  for (int kc = 0; kc < 8; ++kc) {
    s8v b = *reinterpret_cast<const s8v*>(BpD1 + ((size_t)(kc*4 + w)*64 + lane)*8);
    #pragma unroll
    for (int mt = 0; mt < 2; ++mt) {
      s8v af = *reinterpret_cast<const s8v*>(&ldsZ[(mt*16 + i15)*264 + kc*32 + q*8]);
      a1[mt] = __builtin_amdgcn_mfma_f32_16x16x32_bf16(af, b, a1[mt], 0,0,0);
    }
  }
  const float bb1 = bd1[w*16 + i15];
  #pragma unroll
  for (int mt = 0; mt < 2; ++mt)
    #pragma unroll
    for (int r = 0; r < 4; ++r)
      ldsH2[(mt*16 + q*4 + r)*72 + w*16 + i15] = f2bf(seluf(a1[mt][r] + bb1));
  __syncthreads();

  // D2: h2[32x64] @ Wd2[64x64] + bd2 -> fp32 out
  f4v a2[2];
  #pragma unroll
  for (int mt = 0; mt < 2; ++mt) a2[mt] = (f4v){0.f,0.f,0.f,0.f};
  #pragma unroll
  for (int kc = 0; kc < 2; ++kc) {
    s8v b = *reinterpret_cast<const s8v*>(BpD2 + ((size_t)(kc*4 + w)*64 + lane)*8);
    #pragma unroll
    for (int mt = 0; mt < 2; ++mt) {
      s8v af = *reinterpret_cast<const s8v*>(&ldsH2[(mt*16 + i15)*72 + kc*32 + q*8]);
      a2[mt] = __builtin_amdgcn_mfma_f32_16x16x32_bf16(af, b, a2[mt], 0,0,0);
    }
  }
  const float bb2 = bd2[w*16 + i15];
  #pragma unroll
  for (int mt = 0; mt < 2; ++mt)
    #pragma unroll
    for (int r = 0; r < 4; ++r)
      outp[(size_t)(rb + mt*16 + q*4 + r)*64 + w*16 + i15] = a2[mt][r] + bb2;  // FP32
}

// Diagnostic sentinel (should never fire; ws proven >= 84 MB).
__global__ __launch_bounds__(256) void zero_kernel(uint4* __restrict__ outp, int n16)
{
  int i = blockIdx.x*256 + threadIdx.x;
  if (i < n16) outp[i] = (uint4){0u,0u,0u,0u};
}

// ---------------------------------------------------------------------------
extern "C" void kernel_launch(void* const* d_in, const int* in_sizes, int n_in,
                              void* d_out, int out_size, void* d_ws, size_t ws_size,
                              hipStream_t stream)
{
  (void)n_in;
  const float* x   = (const float*)d_in[0];
  const float* Wc  = (const float*)d_in[1];
  const float* Wf  = (const float*)d_in[2];
  const float* Wg  = (const float*)d_in[3];
  const float* Wr  = (const float*)d_in[4];
  const float* br  = (const float*)d_in[5];
  const float* Ws  = (const float*)d_in[6];
  const float* bs  = (const float*)d_in[7];
  const float* Wd1 = (const float*)d_in[8];
  const float* bd1 = (const float*)d_in[9];
  const float* Wd2 = (const float*)d_in[10];
  const float* bd2 = (const float*)d_in[11];

  const size_t ROWS = (size_t)in_sizes[0] / 64;     // B*T = 32768
  const int gridC = (int)(ROWS / 64);               // 512  (conv0)
  const int gridL = (int)(ROWS / 32);               // 1024 (layers)
  const int nT8C = (gridC % 8 == 0) ? gridC / 8 : 0;
  const int nT8L = (gridL % 8 == 0) ? gridL / 8 : 0;

  const size_t packsB = (size_t)6248 * 512 * 2;     // 6.4 MB
  const size_t bfBuf  = ROWS * 256 * 2;             // 16.78 MB
  const size_t needB = packsB + 3*bfBuf;            // 56.7 MB

  if (ws_size < needB) {
    int n16 = (out_size * 4) / 16;                  // fp32 out
    zero_kernel<<<(n16 + 255)/256, 256, 0, stream>>>((uint4*)d_out, n16);
    return;
  }

  char* ws = (char*)d_ws;
  u16* Bp1    = (u16*)ws;            ws += (size_t)4096*512*2;
  u16* Bp2    = (u16*)ws;            ws += (size_t)2048*512*2;
  u16* Bp0    = (u16*)ws;            ws += (size_t)64*512*2;
  u16* BpD1   = (u16*)ws;            ws += (size_t)32*512*2;
  u16* BpD2   = (u16*)ws;            ws += (size_t)8*512*2;
  u16* skipB  = (u16*)ws;            ws += bfBuf;
  u16* bufA   = (u16*)ws;            ws += bfBuf;
  u16* bufB   = (u16*)ws;            ws += bfBuf;

  pack_kernel<<<1562, 256, 0, stream>>>(Wc, Wf, Wg, Wr, Ws, Wd1, Wd2,
                                        Bp1, Bp2, Bp0, BpD1, BpD2);
  conv0_kernel<<<gridC, 256, 0, stream>>>(x, bufA, Bp0, nT8C);
  u16* bufs[2] = {bufA, bufB};
  for (int i = 0; i < 8; ++i) {
    layer_kernel<<<gridL, 256, 0, stream>>>(
        bufs[i & 1], bufs[(i + 1) & 1], skipB,
        Bp1 + (size_t)i*262144, Bp2 + (size_t)i*131072,
        br + i*256, bs + i*256,
        BpD1, BpD2, bd1, bd2, (float*)d_out,
        2 << i, (i == 0) ? 1 : 0, (i == 7) ? 1 : 0, nT8L);
  }
}

// Round 14
// 477.806 us; speedup vs baseline: 1.0885x; 1.0885x over previous
//
#include <hip/hip_runtime.h>
#include <cstdint>

typedef unsigned short u16;
typedef unsigned int u32;
typedef __attribute__((ext_vector_type(8))) short s8v;   // 8 bf16 (4 VGPRs)
typedef __attribute__((ext_vector_type(4))) float f4v;   // MFMA acc

#define FCH 256

__device__ __forceinline__ float bf2f(u16 u){ return __uint_as_float(((u32)u)<<16); }
__device__ __forceinline__ u16 f2bf(float x){
  u32 u = __float_as_uint(x);
  u += 0x7fffu + ((u>>16)&1u);
  return (u16)(u>>16);
}
// Fast reciprocal (v_rcp_f32, ~1e-5 rel err; bf16 outputs tolerate easily).
__device__ __forceinline__ float rcpf(float x){ return __builtin_amdgcn_rcpf(x); }
__device__ __forceinline__ uint4 pack8(float4 a, float4 b){
  uint4 o;
  o.x = (u32)f2bf(a.x) | ((u32)f2bf(a.y)<<16);
  o.y = (u32)f2bf(a.z) | ((u32)f2bf(a.w)<<16);
  o.z = (u32)f2bf(b.x) | ((u32)f2bf(b.y)<<16);
  o.w = (u32)f2bf(b.z) | ((u32)f2bf(b.w)<<16);
  return o;
}
__device__ __forceinline__ float seluf(float x){
  const float sc = 1.0507009873554805f, al = 1.6732632423543772f;
  return x > 0.f ? sc*x : sc*al*(__expf(x)-1.f);
}
// Masked 16B load: AND each dword with m (m=0 zeroes the fragment).
__device__ __forceinline__ s8v ldmask(const u16* p, u32 m){
  uint4 r = *reinterpret_cast<const uint4*>(p);
  r.x &= m; r.y &= m; r.z &= m; r.w &= m;
  s8v v; *reinterpret_cast<uint4*>(&v) = r;
  return v;
}
// XCD-stripe swizzle.
__device__ __forceinline__ int xcd_tile(int bid, int nT8){
  return nT8 ? ((bid & 7) * nT8 + (bid >> 3)) : bid;
}

// ---------------------------------------------------------------------------
// Weight packing (fp32 -> bf16 fragments): lane l slot j of frag (kc,nt) =
// B[kc*32 + (l>>4)*8 + j][nt*16 + (l&15)]  (16B/lane contiguous)
// ---------------------------------------------------------------------------
__global__ __launch_bounds__(256) void pack_kernel(
    const float* __restrict__ Wc, const float* __restrict__ Wf, const float* __restrict__ Wg,
    const float* __restrict__ Wr, const float* __restrict__ Ws,
    const float* __restrict__ Wd1, const float* __restrict__ Wd2,
    u16* __restrict__ Bp1, u16* __restrict__ Bp2, u16* __restrict__ Bp0,
    u16* __restrict__ BpD1, u16* __restrict__ BpD2)
{
  int gid = blockIdx.x*256 + threadIdx.x;
  int frag = gid >> 6;
  int lane = gid & 63;
  int q = lane >> 4, i15 = lane & 15;
  u16 v[8];
  u16* dst;
  if (frag < 4096) {                       // Bp1: [Wf|Wg] K=512 (tap-major)
    int layer = frag >> 9, rem = frag & 511;
    int kc = rem >> 5, nt = rem & 31;
    int n = nt*16 + i15;
    const float* W = (n < 256) ? Wf : Wg;
    int nn = (n < 256) ? n : n - 256;
    #pragma unroll
    for (int j = 0; j < 8; ++j) {
      int k = kc*32 + q*8 + j;
      int tap = k >> 8, cin = k & 255;
      v[j] = f2bf(W[((size_t)((layer*2 + tap)*256 + cin))*256 + nn]);
    }
    dst = Bp1 + (size_t)frag*512 + lane*8;
  } else if (frag < 6144) {                // Bp2: [Wr|Ws] K=256
    int f = frag - 4096;
    int layer = f >> 8, rem = f & 255;
    int kc = rem >> 5, nt = rem & 31;
    int n = nt*16 + i15;
    const float* W = (n < 256) ? Wr : Ws;
    int nn = (n < 256) ? n : n - 256;
    #pragma unroll
    for (int j = 0; j < 8; ++j) {
      int k = kc*32 + q*8 + j;
      v[j] = f2bf(W[((size_t)(layer*256 + k))*256 + nn]);
    }
    dst = Bp2 + (size_t)f*512 + lane*8;
  } else if (frag < 6208) {                // Bp0: Wc K=128
    int f = frag - 6144;
    int kc = f >> 4, nt = f & 15;
    int n = nt*16 + i15;
    #pragma unroll
    for (int j = 0; j < 8; ++j) {
      int k = kc*32 + q*8 + j;
      int tap = k >> 6, cin = k & 63;
      v[j] = f2bf(Wc[(size_t)(tap*64 + cin)*256 + n]);
    }
    dst = Bp0 + (size_t)f*512 + lane*8;
  } else if (frag < 6240) {                // BpD1: Wd1 [256,64]
    int f = frag - 6208;
    int kc = f >> 2, nt = f & 3;
    int n = nt*16 + i15;
    #pragma unroll
    for (int j = 0; j < 8; ++j) {
      int k = kc*32 + q*8 + j;
      v[j] = f2bf(Wd1[(size_t)k*64 + n]);
    }
    dst = BpD1 + (size_t)f*512 + lane*8;
  } else if (frag < 6248) {                // BpD2: Wd2 [64,64]
    int f = frag - 6240;
    int kc = f >> 2, nt = f & 3;
    int n = nt*16 + i15;
    #pragma unroll
    for (int j = 0; j < 8; ++j) {
      int k = kc*32 + q*8 + j;
      v[j] = f2bf(Wd2[(size_t)k*64 + n]);
    }
    dst = BpD2 + (size_t)f*512 + lane*8;
  } else return;
  uint4 o;
  o.x = (u32)v[0] | ((u32)v[1] << 16);
  o.y = (u32)v[2] | ((u32)v[3] << 16);
  o.z = (u32)v[4] | ((u32)v[5] << 16);
  o.w = (u32)v[6] | ((u32)v[7] << 16);
  *reinterpret_cast<uint4*>(dst) = o;
}

// ---------------------------------------------------------------------------
// Initial causal conv (dilation 1, no bias): out0 = [x[t-1]|x[t]] @ cat(Wc)
// ---------------------------------------------------------------------------
__global__ __launch_bounds__(256, 2) void conv0_kernel(
    const float* __restrict__ x, u16* __restrict__ outBf,
    const u16* __restrict__ Bp0, int nT8)
{
  __shared__ __align__(16) u16 ldsA[2][2048];
  const int tid = threadIdx.x;
  const int w = tid >> 6, lane = tid & 63, q = lane >> 4, i15 = lane & 15;
  const int rb = xcd_tile(blockIdx.x, nT8) * 64;
  const int sm = tid >> 2, sg = tid & 3;
  const int grow = rb + sm;
  const int tpos = grow & 4095;
  const int sunit = ((sm >> 4)*64 + sg*16 + ((sm & 15) ^ (sg << 1))) * 8;
  const int runit = (q*16 + (i15 ^ (q << 1))) * 8;

  f4v acc[4][4];
  #pragma unroll
  for (int jj = 0; jj < 4; ++jj)
    #pragma unroll
    for (int mt = 0; mt < 4; ++mt)
      acc[jj][mt] = (f4v){0.f,0.f,0.f,0.f};

  float4 f0 = {0.f,0.f,0.f,0.f}, f1 = {0.f,0.f,0.f,0.f};
  if (tpos >= 1) {
    const float* px = x + (size_t)(grow-1)*64 + sg*8;
    f0 = *reinterpret_cast<const float4*>(px);
    f1 = *reinterpret_cast<const float4*>(px + 4);
  }
  *reinterpret_cast<uint4*>(&ldsA[0][sunit]) = pack8(f0, f1);
  s8v bcur[4], bnxt[4];
  #pragma unroll
  for (int jj = 0; jj < 4; ++jj)
    bcur[jj] = *reinterpret_cast<const s8v*>(Bp0 + ((size_t)(w + 4*jj)*64 + lane)*8);
  __syncthreads();

  for (int kc = 0; kc < 4; ++kc) {
    const int cur = kc & 1;
    uint4 an = {0u,0u,0u,0u};
    if (kc < 3) {
      int kg = (kc+1)*32 + sg*8;
      int tap = kg >> 6, col = kg & 63;
      float4 g0 = {0.f,0.f,0.f,0.f}, g1 = {0.f,0.f,0.f,0.f};
      if (tap) {
        const float* px = x + (size_t)grow*64 + col;
        g0 = *reinterpret_cast<const float4*>(px);
        g1 = *reinterpret_cast<const float4*>(px + 4);
      } else if (tpos >= 1) {
        const float* px = x + (size_t)(grow-1)*64 + col;
        g0 = *reinterpret_cast<const float4*>(px);
        g1 = *reinterpret_cast<const float4*>(px + 4);
      }
      an = pack8(g0, g1);
      #pragma unroll
      for (int jj = 0; jj < 4; ++jj)
        bnxt[jj] = *reinterpret_cast<const s8v*>(Bp0 + (((size_t)(kc+1)*16 + (w + 4*jj))*64 + lane)*8);
    }
    s8v af[4];
    #pragma unroll
    for (int mt = 0; mt < 4; ++mt)
      af[mt] = *reinterpret_cast<const s8v*>(&ldsA[cur][mt*512 + runit]);
    #pragma unroll
    for (int jj = 0; jj < 4; ++jj)
      #pragma unroll
      for (int mt = 0; mt < 4; ++mt)
        acc[jj][mt] = __builtin_amdgcn_mfma_f32_16x16x32_bf16(af[mt], bcur[jj], acc[jj][mt], 0,0,0);
    if (kc < 3) {
      *reinterpret_cast<uint4*>(&ldsA[cur ^ 1][sunit]) = an;
      #pragma unroll
      for (int jj = 0; jj < 4; ++jj) bcur[jj] = bnxt[jj];
    }
    __syncthreads();
  }

  #pragma unroll
  for (int jj = 0; jj < 4; ++jj) {
    const int cc = (w + 4*jj)*16 + i15;
    #pragma unroll
    for (int mt = 0; mt < 4; ++mt)
      #pragma unroll
      for (int r = 0; r < 4; ++r) {
        const int g2 = rb + mt*16 + q*4 + r;
        outBf[(size_t)g2*FCH + cc] = f2bf(acc[jj][mt][r]);
      }
  }
}

// ---------------------------------------------------------------------------
// One WaveNet residual layer -- EXACT R12 hot path (M=32, 256 thr, 1024
// blocks, A 4-slot ring lead-3, B dist-2 half-chunk, one barrier, rcpf,
// readfirstlane, skv loaded in EPILOGUE as in R12).  Single change vs R12:
// when last==1, the row-local final head is fused after the epilogue
// (selu(skip)->ldsZ -> @Wd1+bd1,selu -> ldsH2 -> @Wd2+bd2 -> fp32 out),
// replacing the separate final_kernel. Head code lives entirely after
// `if (!last) return` so its registers don't overlap the hot loop.
// ---------------------------------------------------------------------------
__global__ __launch_bounds__(256, 3) void layer_kernel(
    const u16* __restrict__ inBf, u16* __restrict__ outBf,
    u16* __restrict__ skipB,
    const u16* __restrict__ Bp1, const u16* __restrict__ Bp2,
    const float* __restrict__ br, const float* __restrict__ bs,
    const u16* __restrict__ BpD1, const u16* __restrict__ BpD2,
    const float* __restrict__ bd1, const float* __restrict__ bd2,
    float* __restrict__ outp,
    int dil, int first, int last, int nT8)
{
  __shared__ __align__(16) u16 ldsZ[32*264];     // 16.9 KB (reused as H when last)
  __shared__ __align__(16) u16 ldsH2[32*72];     // 4.6 KB (head only)
  const int tid = threadIdx.x;
  const int w = __builtin_amdgcn_readfirstlane(tid >> 6);   // wave-uniform -> SGPR
  const int lane = tid & 63, q = lane >> 4, i15 = lane & 15;
  const int rb = xcd_tile(blockIdx.x, nT8) * 32;

  f4v acc[8][2];   // [jj: nt=w+4*jj][mt]
  #pragma unroll
  for (int jj = 0; jj < 8; ++jj)
    #pragma unroll
    for (int mt = 0; mt < 2; ++mt)
      acc[jj][mt] = (f4v){0.f,0.f,0.f,0.f};

  // ---------------- stage 1: A 4-slot ring (3-chunk lead), B dist-2 ---------
  {
    const u16* a0p[2];   // tap0: row t-dil (safe addr; mask zeroes invalid)
    const u16* a1p[2];   // tap1: row t
    u32 am[2];
    #pragma unroll
    for (int mt = 0; mt < 2; ++mt) {
      const int row = rb + mt*16 + i15;
      const bool v = (row & 4095) >= dil;
      a0p[mt] = inBf + (size_t)(v ? row - dil : row)*FCH + q*8;
      a1p[mt] = inBf + (size_t)row*FCH + q*8;
      am[mt]  = v ? 0xffffffffu : 0u;
    }

    s8v bb[3][4], aa[4][2];
    // prologue B: steps 0,1 (chunk 0 halves); prologue A: chunks 0,1,2
    #pragma unroll
    for (int j2 = 0; j2 < 4; ++j2) {
      bb[0][j2] = *reinterpret_cast<const s8v*>(Bp1 + ((size_t)(w + 4*j2)*64 + lane)*8);
      bb[1][j2] = *reinterpret_cast<const s8v*>(Bp1 + ((size_t)(w + 16 + 4*j2)*64 + lane)*8);
    }
    #pragma unroll
    for (int c = 0; c < 3; ++c)
      #pragma unroll
      for (int mt = 0; mt < 2; ++mt)
        aa[c][mt] = ldmask(a0p[mt] + c*32, am[mt]);

    #pragma unroll
    for (int s = 0; s < 32; ++s) {
      const int kc = s >> 1, h = s & 1;
      if (s + 2 < 32) {                      // B: dist-2 half-chunk prefetch
        const int sp = s + 2, kcp = sp >> 1, hp = sp & 1;
        #pragma unroll
        for (int j2 = 0; j2 < 4; ++j2)
          bb[sp % 3][j2] = *reinterpret_cast<const s8v*>(
              Bp1 + (((size_t)kcp*32 + (w + 16*hp + 4*j2))*64 + lane)*8);
      }
      if (h == 0 && kc + 3 < 16) {           // A: 3-chunk (6-step) lead
        const int ca = kc + 3;               // slot (ca&3)=(kc-1)&3: consumer
        if (ca < 8) {                        // finished at step 2kc-1  -> safe
          #pragma unroll
          for (int mt = 0; mt < 2; ++mt)
            aa[ca & 3][mt] = ldmask(a0p[mt] + ca*32, am[mt]);
        } else {
          #pragma unroll
          for (int mt = 0; mt < 2; ++mt)
            aa[ca & 3][mt] = *reinterpret_cast<const s8v*>(a1p[mt] + (ca - 8)*32);
        }
      }
      __builtin_amdgcn_s_setprio(1);
      #pragma unroll
      for (int j2 = 0; j2 < 4; ++j2)
        #pragma unroll
        for (int mt = 0; mt < 2; ++mt)
          acc[h*4 + j2][mt] = __builtin_amdgcn_mfma_f32_16x16x32_bf16(
              aa[kc & 3][mt], bb[s % 3][j2], acc[h*4 + j2][mt], 0,0,0);
      __builtin_amdgcn_s_setprio(0);
    }
  }

  // -------- issue stage-2 steps 0,1 B loads now (latency hides under exp) ---
  s8v s2b[3][4];
  #pragma unroll
  for (int j2 = 0; j2 < 4; ++j2) {
    s2b[0][j2] = *reinterpret_cast<const s8v*>(Bp2 + ((size_t)(w + 4*j2)*64 + lane)*8);
    s2b[1][j2] = *reinterpret_cast<const s8v*>(Bp2 + ((size_t)(w + 16 + 4*j2)*64 + lane)*8);
  }

  // ---------------- activation: Z -> LDS (C-layout -> row-major) ------------
  #pragma unroll
  for (int jj = 0; jj < 4; ++jj) {
    const int colb = (w + 4*jj)*16 + i15;
    #pragma unroll
    for (int mt = 0; mt < 2; ++mt)
      #pragma unroll
      for (int r = 0; r < 4; ++r) {
        float f = acc[jj][mt][r];
        float g = acc[jj+4][mt][r];
        float z = (1.f - 2.f*rcpf(__expf(2.f*f) + 1.f)) * rcpf(1.f + __expf(-g));
        ldsZ[(mt*16 + q*4 + r)*264 + colb] = f2bf(z);
      }
  }
  // zero acc for stage 2 (residual/skip/bias added in epilogue, f32)
  #pragma unroll
  for (int jj = 0; jj < 8; ++jj)
    #pragma unroll
    for (int mt = 0; mt < 2; ++mt)
      acc[jj][mt] = (f4v){0.f,0.f,0.f,0.f};
  __syncthreads();

  // ---------------- stage 2: half-chunk dist-2 (B global, A LDS) ------------
  {
    s8v zf[2][2];
    #pragma unroll
    for (int mt = 0; mt < 2; ++mt)
      zf[0][mt] = *reinterpret_cast<const s8v*>(&ldsZ[(mt*16 + i15)*264 + q*8]);
    #pragma unroll
    for (int s = 0; s < 16; ++s) {
      const int kc = s >> 1, h = s & 1;
      if (s + 2 < 16) {
        const int sp = s + 2, kcp = sp >> 1, hp = sp & 1;
        #pragma unroll
        for (int j2 = 0; j2 < 4; ++j2)
          s2b[sp % 3][j2] = *reinterpret_cast<const s8v*>(
              Bp2 + (((size_t)kcp*32 + (w + 16*hp + 4*j2))*64 + lane)*8);
        if (hp == 0) {
          #pragma unroll
          for (int mt = 0; mt < 2; ++mt)
            zf[kcp & 1][mt] = *reinterpret_cast<const s8v*>(&ldsZ[(mt*16 + i15)*264 + kcp*32 + q*8]);
        }
      }
      __builtin_amdgcn_s_setprio(1);
      #pragma unroll
      for (int j2 = 0; j2 < 4; ++j2)
        #pragma unroll
        for (int mt = 0; mt < 2; ++mt)
          acc[h*4 + j2][mt] = __builtin_amdgcn_mfma_f32_16x16x32_bf16(
              zf[kc & 1][mt], s2b[s % 3][j2], acc[h*4 + j2][mt], 0,0,0);
      __builtin_amdgcn_s_setprio(0);
    }
  }

  if (!last) {
    // ---------------- epilogue (R12-identical): res/skip load late ----------
    u16 resv[4][2][4], skv[4][2][4];
    #pragma unroll
    for (int jj = 0; jj < 4; ++jj) {
      const int cc = (w + 4*jj)*16 + i15;
      #pragma unroll
      for (int mt = 0; mt < 2; ++mt)
        #pragma unroll
        for (int r = 0; r < 4; ++r)
          resv[jj][mt][r] = inBf[(size_t)(rb + mt*16 + q*4 + r)*FCH + cc];
    }
    if (!first) {
      #pragma unroll
      for (int jj = 0; jj < 4; ++jj) {
        const int cc = (w + 4*jj)*16 + i15;
        #pragma unroll
        for (int mt = 0; mt < 2; ++mt)
          #pragma unroll
          for (int r = 0; r < 4; ++r)
            skv[jj][mt][r] = skipB[(size_t)(rb + mt*16 + q*4 + r)*FCH + cc];
      }
    }
    #pragma unroll
    for (int jj = 0; jj < 8; ++jj) {
      const int nt = w + 4*jj;
      const bool isR = (jj < 4);
      const int cc = (isR ? nt*16 : (nt-16)*16) + i15;
      const float bias = isR ? br[cc] : bs[cc];
      #pragma unroll
      for (int mt = 0; mt < 2; ++mt)
        #pragma unroll
        for (int r = 0; r < 4; ++r) {
          const int g2 = rb + mt*16 + q*4 + r;
          float vv = acc[jj][mt][r] + bias;
          if (isR) vv += bf2f(resv[jj][mt][r]);
          else if (!first) vv += bf2f(skv[jj-4][mt][r]);
          u16 hv = f2bf(vv);
          if (isR) outBf[(size_t)g2*FCH + cc] = hv;
          else     skipB[(size_t)g2*FCH + cc] = hv;
        }
    }
    return;
  }

  // ================= last layer: fused final head ===========================
  // skip value = acc[4..7] + bs + old skip; residual out is dead.
  {
    u16 skv[4][2][4];
    #pragma unroll
    for (int jj = 0; jj < 4; ++jj) {
      const int cc = (w + 4*jj)*16 + i15;
      #pragma unroll
      for (int mt = 0; mt < 2; ++mt)
        #pragma unroll
        for (int r = 0; r < 4; ++r)
          skv[jj][mt][r] = skipB[(size_t)(rb + mt*16 + q*4 + r)*FCH + cc];
    }
    __syncthreads();   // all stage-2 ldsZ reads complete before overwrite
    // H = selu(skip_final) -> ldsZ (row-major, stride 264)
    #pragma unroll
    for (int jj = 4; jj < 8; ++jj) {
      const int cc = ((w + 4*jj) - 16)*16 + i15;
      const float bias = bs[cc];
      #pragma unroll
      for (int mt = 0; mt < 2; ++mt)
        #pragma unroll
        for (int r = 0; r < 4; ++r) {
          float vv = acc[jj][mt][r] + bias + bf2f(skv[jj-4][mt][r]);
          ldsZ[(mt*16 + q*4 + r)*264 + cc] = f2bf(seluf(vv));
        }
    }
  }
  __syncthreads();

  // D1: h[32x256] @ Wd1[256x64] + bd1, selu -> ldsH2 (stride 72)
  f4v a1[2];
  #pragma unroll
  for (int mt = 0; mt < 2; ++mt) a1[mt] = (f4v){0.f,0.f,0.f,0.f};
  for (int kc = 0; kc < 8; ++kc) {
    s8v b = *reinterpret_cast<const s8v*>(BpD1 + ((size_t)(kc*4 + w)*64 + lane)*8);
    #pragma unroll
    for (int mt = 0; mt < 2; ++mt) {
      s8v af = *reinterpret_cast<const s8v*>(&ldsZ[(mt*16 + i15)*264 + kc*32 + q*8]);
      a1[mt] = __builtin_amdgcn_mfma_f32_16x16x32_bf16(af, b, a1[mt], 0,0,0);
    }
  }
  const float bb1 = bd1[w*16 + i15];
  #pragma unroll
  for (int mt = 0; mt < 2; ++mt)
    #pragma unroll
    for (int r = 0; r < 4; ++r)
      ldsH2[(mt*16 + q*4 + r)*72 + w*16 + i15] = f2bf(seluf(a1[mt][r] + bb1));
  __syncthreads();

  // D2: h2[32x64] @ Wd2[64x64] + bd2 -> fp32 out
  f4v a2[2];
  #pragma unroll
  for (int mt = 0; mt < 2; ++mt) a2[mt] = (f4v){0.f,0.f,0.f,0.f};
  #pragma unroll
  for (int kc = 0; kc < 2; ++kc) {
    s8v b = *reinterpret_cast<const s8v*>(BpD2 + ((size_t)(kc*4 + w)*64 + lane)*8);
    #pragma unroll
    for (int mt = 0; mt < 2; ++mt) {
      s8v af = *reinterpret_cast<const s8v*>(&ldsH2[(mt*16 + i15)*72 + kc*32 + q*8]);
      a2[mt] = __builtin_amdgcn_mfma_f32_16x16x32_bf16(af, b, a2[mt], 0,0,0);
    }
  }
  const float bb2 = bd2[w*16 + i15];
  #pragma unroll
  for (int mt = 0; mt < 2; ++mt)
    #pragma unroll
    for (int r = 0; r < 4; ++r)
      outp[(size_t)(rb + mt*16 + q*4 + r)*64 + w*16 + i15] = a2[mt][r] + bb2;  // FP32
}

// Diagnostic sentinel (should never fire; ws proven >= 84 MB).
__global__ __launch_bounds__(256) void zero_kernel(uint4* __restrict__ outp, int n16)
{
  int i = blockIdx.x*256 + threadIdx.x;
  if (i < n16) outp[i] = (uint4){0u,0u,0u,0u};
}

// ---------------------------------------------------------------------------
extern "C" void kernel_launch(void* const* d_in, const int* in_sizes, int n_in,
                              void* d_out, int out_size, void* d_ws, size_t ws_size,
                              hipStream_t stream)
{
  (void)n_in;
  const float* x   = (const float*)d_in[0];
  const float* Wc  = (const float*)d_in[1];
  const float* Wf  = (const float*)d_in[2];
  const float* Wg  = (const float*)d_in[3];
  const float* Wr  = (const float*)d_in[4];
  const float* br  = (const float*)d_in[5];
  const float* Ws  = (const float*)d_in[6];
  const float* bs  = (const float*)d_in[7];
  const float* Wd1 = (const float*)d_in[8];
  const float* bd1 = (const float*)d_in[9];
  const float* Wd2 = (const float*)d_in[10];
  const float* bd2 = (const float*)d_in[11];

  const size_t ROWS = (size_t)in_sizes[0] / 64;     // B*T = 32768
  const int gridC = (int)(ROWS / 64);               // 512  (conv0)
  const int gridL = (int)(ROWS / 32);               // 1024 (layers)
  const int nT8C = (gridC % 8 == 0) ? gridC / 8 : 0;
  const int nT8L = (gridL % 8 == 0) ? gridL / 8 : 0;

  const size_t packsB = (size_t)6248 * 512 * 2;     // 6.4 MB
  const size_t bfBuf  = ROWS * 256 * 2;             // 16.78 MB
  const size_t needB = packsB + 3*bfBuf;            // 56.7 MB

  if (ws_size < needB) {
    int n16 = (out_size * 4) / 16;                  // fp32 out
    zero_kernel<<<(n16 + 255)/256, 256, 0, stream>>>((uint4*)d_out, n16);
    return;
  }

  char* ws = (char*)d_ws;
  u16* Bp1    = (u16*)ws;            ws += (size_t)4096*512*2;
  u16* Bp2    = (u16*)ws;            ws += (size_t)2048*512*2;
  u16* Bp0    = (u16*)ws;            ws += (size_t)64*512*2;
  u16* BpD1   = (u16*)ws;            ws += (size_t)32*512*2;
  u16* BpD2   = (u16*)ws;            ws += (size_t)8*512*2;
  u16* skipB  = (u16*)ws;            ws += bfBuf;
  u16* bufA   = (u16*)ws;            ws += bfBuf;
  u16* bufB   = (u16*)ws;            ws += bfBuf;

  pack_kernel<<<1562, 256, 0, stream>>>(Wc, Wf, Wg, Wr, Ws, Wd1, Wd2,
                                        Bp1, Bp2, Bp0, BpD1, BpD2);
  conv0_kernel<<<gridC, 256, 0, stream>>>(x, bufA, Bp0, nT8C);
  u16* bufs[2] = {bufA, bufB};
  for (int i = 0; i < 8; ++i) {
    layer_kernel<<<gridL, 256, 0, stream>>>(
        bufs[i & 1], bufs[(i + 1) & 1], skipB,
        Bp1 + (size_t)i*262144, Bp2 + (size_t)i*131072,
        br + i*256, bs + i*256,
        BpD1, BpD2, bd1, bd2, (float*)d_out,
        2 << i, (i == 0) ? 1 : 0, (i == 7) ? 1 : 0, nT8L);
  }
}